// Round 13
// baseline (254.999 us; speedup 1.0000x reference)
//
#include <hip/hip_runtime.h>
#include <math.h>

#define HID 50
#define TT  512
#define BT  16      // batch per block (= MFMA N)
#define NCW 7       // 7 waves, TWO 16-row M-tiles each; wave 6 tile-13 = y-tile
#define NTH 448     // 7 waves
#define HS  72      // H plane row stride in shorts (144 B, 16B-aligned)
#define L2E 1.44269504088896f
#define K2C 2.88539008177793f   // 2*log2(e)

typedef __attribute__((ext_vector_type(8))) short bf16x8;
typedef __attribute__((ext_vector_type(4))) float f32x4;

__device__ __forceinline__ unsigned short bf16_rtne(float f) {
    unsigned u = __float_as_uint(f);
    u = (u + 0x7FFFu + ((u >> 16) & 1u)) >> 16;
    return (unsigned short)u;
}
__device__ __forceinline__ float bf16_f32(unsigned short s) {
    return __uint_as_float(((unsigned)s) << 16);
}

// R25 = R24 (181.5 µs) minus the chore wave: y folded into wave 6's
// FULLY-PHANTOM tile 13 (rows 208..223).
//  - tile 13's A rows 0,1 (gh 208,209) = raw hi(W_out) / lo(W_out), k<50.
//    Wave 6's existing a1 MFMA chain then emits y_hi/y_lo in a1.x/a1.y of
//    quad-0 lanes (D rows 0,1) -> those lanes store y. Identical math to
//    R24's chore MFMA (proven). Unlike R22, the y-tile has NO real units.
//  - y-tile GATES provably inert: Eg=exp2(0)=1 -> t1=0 -> cs1 stays
//    exactly 0 -> h1=0 -> dump slots 57..60 (A zero there).
//  - x-duty on wave 6's quad-3 lanes (tile-12 uoa=51->dump56, tile-13
//    phantom: fully inert lanes). Same register xa pipeline.
//  => 8 -> 7 waves: -1 barrier participant, -2KB/step LDS reads, -2 MFMAs.
// Carries: lgkm-only barrier (R20), unroll x2 + hoisted ptrs + cvt_pk
// (R21), chained MFMA (R23), ILP-2 tiles (R24).
//
// Math (A rows pre-scaled by log2e for i,f,o / 2*log2e for g; y rows RAW):
//   Ei=2^-i', Ef=2^-f', Eg=2^g', Eo=2^-o'
//   cs = [cs*(1+Ei)(1+Eg) + K2*(Eg-1)*(1+Ef)] * rcp((1+Ef)(1+Ei)(1+Eg))
//   Ec = 2^cs;  h = (Ec-1) * rcp((1+Eo)(1+Ec))
// K-slots: 0..49 = s*W_hh | 50 = (s*Wih)_hi (x_hi) | 51 = (s*bias)_hi (1.0)
//          52 = (s*Wih)_hi (x_lo) | 53 = (s*bias)_lo (1.0) | 54 = (s*Wih)_lo (x_hi)
//          55..60 = phantom-h dump (always 0; A zero there)
__global__ __launch_bounds__(NTH, 1) void lstm_mfma18_kernel(
    const float* __restrict__ x,      // [B, T]
    const float* __restrict__ W_ih,   // [200, 1]
    const float* __restrict__ W_hh,   // [200, 50]
    const float* __restrict__ b_ih,   // [200]
    const float* __restrict__ b_hh,   // [200]
    const float* __restrict__ W_out,  // [1, 50]
    const float* __restrict__ b_out,  // [1]
    float* __restrict__ out)          // [B, T]
{
    const int tid  = threadIdx.x;
    const int lane = tid & 63;
    const int wv   = tid >> 6;       // 0..6
    const int col  = lane & 15;      // A-m / B-n(batch) / D-col(batch)
    const int quad = lane >> 4;      // k-octet / D row-group

    __shared__ __align__(16) unsigned short Hh[2][BT][HS];

    // zero both H buffers (k-slots 55..63 + pads stay 0)
    for (int i = tid; i < 2 * BT * HS; i += NTH)
        (&Hh[0][0][0])[i] = 0;

    // persistent A fragments: [tile][kk] (single plane, PRE-SCALED rows)
    bf16x8 Ah[2][2];
    float cs0 = 0.f, cs1 = 0.f;                // 2*log2e * c per tile
    const int uoa = (wv * 2) * 4 + quad;
    const int uob = (wv * 2 + 1) * 4 + quad;
    const int uo2a = (uoa < HID) ? uoa : uoa + 5;   // 50,51 -> 55,56
    const int uo2b = (uob < HID) ? uob : uob + 5;   // 52..55 -> 57..60

    #pragma unroll
    for (int i = 0; i < 2; ++i) {
        if (wv == 6 && i == 1) {
            // tile 13 = y-tile: row0 = hi(W_out), row1 = lo(W_out), RAW
            #pragma unroll
            for (int kk = 0; kk < 2; ++kk) {
                #pragma unroll
                for (int j = 0; j < 8; ++j) {
                    const int k = kk * 32 + quad * 8 + j;
                    float v = 0.f;
                    if (k < HID) {
                        const float w = W_out[k];
                        if (col == 0)      v = w;
                        else if (col == 1) v = w - bf16_f32(bf16_rtne(w));
                    }
                    Ah[1][kk][j] = (short)bf16_rtne(v);
                }
            }
        } else {
            const int gh  = (wv * 2 + i) * 16 + col;   // g^ row
            const int u   = gh >> 2;
            const int ty  = gh & 3;
            const bool vl = (u < HID);
            const int og  = ty * HID + u;              // original gate row
            const float sc = (ty == 2) ? K2C : L2E;
            #pragma unroll
            for (int kk = 0; kk < 2; ++kk) {
                #pragma unroll
                for (int j = 0; j < 8; ++j) {
                    const int k = kk * 32 + quad * 8 + j;
                    float v = 0.f;
                    if (vl) {
                        if (k < HID)      v = sc * W_hh[og * HID + k];
                        else if (k == 50) v = sc * W_ih[og];
                        else if (k == 51) v = sc * (b_ih[og] + b_hh[og]);
                        else if (k == 52) v = sc * W_ih[og];
                        else if (k == 53) {
                            const float sb = sc * (b_ih[og] + b_hh[og]);
                            v = sb - bf16_f32(bf16_rtne(sb));
                        } else if (k == 54) {
                            const float sw = sc * W_ih[og];
                            v = sw - bf16_f32(bf16_rtne(sw));
                        }
                    }
                    Ah[i][kk][j] = (short)bf16_rtne(v);
                }
            }
        }
    }
    const float bo = b_out[0];
    float* yout = out + (size_t)blockIdx.x * BT * TT + (size_t)col * TT;

    // x pipeline state (wave 6, quad-3 lanes own batch b = col)
    const float* xrow = x + (size_t)(blockIdx.x * BT + col) * TT;
    float xa = 0.f;
    if (wv == 6 && lane >= 48)
        xa = xrow[1];                            // x[b][1] for step t=0's write

    __syncthreads();    // zeroed H visible

    // buffer-0 slots for t=0: x_0 hi/lo + bias-1.0 markers (packed b32 writes)
    if (tid < BT) {
        const float x0 = x[(size_t)(blockIdx.x * BT + tid) * TT];
        const unsigned short hx = bf16_rtne(x0);
        const unsigned short lx = bf16_rtne(x0 - bf16_f32(hx));
        unsigned* row32 = (unsigned*)&Hh[0][tid][0];
        row32[25] = (unsigned)hx | (0x3F80u << 16);   // k=50,51
        row32[26] = (unsigned)lx | (0x3F80u << 16);   // k=52,53
        Hh[0][tid][54] = hx;                          // k=54
    }
    __syncthreads();

    // hoisted per-lane pointers (loop-invariant)
    const unsigned short* rdA = &Hh[0][col][quad * 8];   // read plane 0
    const unsigned short* rdB = &Hh[1][col][quad * 8];   // read plane 1
    unsigned short* wrA0 = &Hh[1][col][uo2a];            // write when reading 0
    unsigned short* wrA1 = &Hh[1][col][uo2b];
    unsigned short* wrB0 = &Hh[0][col][uo2a];            // write when reading 1
    unsigned short* wrB1 = &Hh[0][col][uo2b];
    unsigned* xwA = (unsigned*)&Hh[1][col][0];
    unsigned* xwB = (unsigned*)&Hh[0][col][0];
    const f32x4 z = {0.f, 0.f, 0.f, 0.f};

#define GATES(ACC, CS, HOUT)                                                  \
    do {                                                                      \
        const float Ei = __builtin_amdgcn_exp2f(-(ACC).x);                    \
        const float Ef = __builtin_amdgcn_exp2f(-(ACC).y);                    \
        const float Eg = __builtin_amdgcn_exp2f((ACC).z);                     \
        const float Eo = __builtin_amdgcn_exp2f(-(ACC).w);                    \
        const float DIG = (1.f + Ei) * (1.f + Eg);                            \
        const float DF  = 1.f + Ef;                                           \
        const float t1  = fmaf(K2C, Eg, -K2C);                                \
        const float num = fmaf((CS), DIG, t1 * DF);                           \
        (CS) = num * __builtin_amdgcn_rcpf(DF * DIG);                         \
        const float Ec = __builtin_amdgcn_exp2f(CS);                          \
        (HOUT) = (Ec - 1.f) *                                                 \
                 __builtin_amdgcn_rcpf((1.f + Eo) * (1.f + Ec));              \
    } while (0)

#define LSTM_STEP(RD, WR0, WR1, XW, TI)                                       \
    do {                                                                      \
        const bf16x8 B0 = *(const bf16x8*)(RD);                               \
        const bf16x8 B1 = *(const bf16x8*)((RD) + 32);                        \
        if (wv == 6 && lane >= 48) {                                          \
            const unsigned short hx = bf16_rtne(xa);                          \
            const unsigned short lx = bf16_rtne(xa - bf16_f32(hx));           \
            (XW)[25] = (unsigned)hx | (0x3F80u << 16);                        \
            (XW)[26] = (unsigned)lx | (0x3F80u << 16);                        \
            ((unsigned short*)(XW))[54] = hx;                                 \
            xa = xrow[((TI) + 2 < TT) ? (TI) + 2 : TT - 1];                   \
        }                                                                     \
        f32x4 a0 = __builtin_amdgcn_mfma_f32_16x16x32_bf16(Ah[0][0], B0, z, 0, 0, 0); \
        f32x4 a1 = __builtin_amdgcn_mfma_f32_16x16x32_bf16(Ah[1][0], B0, z, 0, 0, 0); \
        a0 = __builtin_amdgcn_mfma_f32_16x16x32_bf16(Ah[0][1], B1, a0, 0, 0, 0); \
        a1 = __builtin_amdgcn_mfma_f32_16x16x32_bf16(Ah[1][1], B1, a1, 0, 0, 0); \
        float h0, h1;                                                         \
        GATES(a0, cs0, h0);                                                   \
        GATES(a1, cs1, h1);                                                   \
        unsigned hpk;                                                         \
        asm("v_cvt_pk_bf16_f32 %0, %1, %2" : "=v"(hpk) : "v"(h0), "v"(h1));   \
        *(WR0) = (unsigned short)(hpk & 0xFFFFu);                             \
        *(WR1) = (unsigned short)(hpk >> 16);                                 \
        if (wv == 6 && lane < 16 && (TI) > 0)                                 \
            yout[(TI) - 1] = a1.x + a1.y + bo;                                \
    } while (0)

    for (int t = 0; t < TT; t += 2) {
        LSTM_STEP(rdA, wrA0, wrA1, xwA, t);        // read plane 0, write plane 1
        asm volatile("s_waitcnt lgkmcnt(0)\n\ts_barrier" ::: "memory");
        LSTM_STEP(rdB, wrB0, wrB1, xwB, t + 1);    // read plane 1, write plane 0
        asm volatile("s_waitcnt lgkmcnt(0)\n\ts_barrier" ::: "memory");
    }
#undef LSTM_STEP
#undef GATES

    // epilogue: y_{TT-1} from plane 0 (h_{511}) via the y-tile chain
    if (wv == 6) {
        const bf16x8 B0 = *(const bf16x8*)rdA;
        const bf16x8 B1 = *(const bf16x8*)(rdA + 32);
        f32x4 a1 = __builtin_amdgcn_mfma_f32_16x16x32_bf16(Ah[1][0], B0, z, 0, 0, 0);
        a1 = __builtin_amdgcn_mfma_f32_16x16x32_bf16(Ah[1][1], B1, a1, 0, 0, 0);
        if (lane < 16)
            yout[TT - 1] = a1.x + a1.y + bo;
    }
}

extern "C" void kernel_launch(void* const* d_in, const int* in_sizes, int n_in,
                              void* d_out, int out_size, void* d_ws, size_t ws_size,
                              hipStream_t stream) {
    const float* x     = (const float*)d_in[0];
    const float* W_ih  = (const float*)d_in[1];
    const float* W_hh  = (const float*)d_in[2];
    const float* b_ih  = (const float*)d_in[3];
    const float* b_hh  = (const float*)d_in[4];
    const float* W_out = (const float*)d_in[5];
    const float* b_out = (const float*)d_in[6];
    float* out = (float*)d_out;

    const int B = in_sizes[0] / TT;          // 4096
    lstm_mfma18_kernel<<<B / BT, NTH, 0, stream>>>(x, W_ih, W_hh, b_ih, b_hh,
                                                   W_out, b_out, out);
}

// Round 14
// 245.621 us; speedup vs baseline: 1.0382x; 1.0382x over previous
//
#include <hip/hip_runtime.h>
#include <math.h>

#define HID 50
#define TT  512
#define BT  16      // batch per block (= MFMA N)
#define NTH 448     // 7 waves: 6 compute (2 tiles each) + 1 mixed
#define HS  72      // H plane row stride in shorts (144 B, 16B-aligned)
#define L2E 1.44269504088896f
#define K2C 2.88539008177793f   // 2*log2(e)

typedef __attribute__((ext_vector_type(8))) short bf16x8;
typedef __attribute__((ext_vector_type(4))) float f32x4;

__device__ __forceinline__ unsigned short bf16_rtne(float f) {
    unsigned u = __float_as_uint(f);
    u = (u + 0x7FFFu + ((u >> 16) & 1u)) >> 16;
    return (unsigned short)u;
}
__device__ __forceinline__ float bf16_f32(unsigned short s) {
    return __uint_as_float(((unsigned)s) << 16);
}

// R26 = R24 (181.5 µs) with the chore wave and wave-6's two sparse tiles
// MERGED into one balanced mixed wave. R25's failure was a straggler
// (full 2-tile compute + x + y on one wave); here the mixed wave does
// LESS compute than the others, so its extra duties fit in the slack:
//  - mixed A-tile: rows 0,1 = hi/lo(W_out) RAW, k<50 (R24-proven y
//    mapping: y = a.x + a.y on quad-0 lanes); rows 4..7 = unit-48 gate
//    rows; rows 8..11 = unit-49; rest zero.
//  - per step: 2 chained MFMAs + ONE lane-uniform GATES. quad-1 lanes
//    produce h[48], quad-2 h[49]; quad-0 (y rows: Eg=1 -> t1=0 -> cs
//    stays exactly 0 -> h=0) and quad-3 (all-zero) dump to slots 55/56.
//  - x-duty on quad-3 lanes; y-store on quad-0 lanes (both low-load).
//  - compute waves 0..5 cover tiles 0..11 = units 0..47, all real (no
//    phantom mapping at all).
//  => 7 waves, balanced: -1 wave of port/skew vs R24, -4 MFMAs.
// Carries: lgkm-only barrier (R20), unroll x2 + hoisted ptrs + cvt_pk
// (R21), chained MFMA (R23), ILP-2 tiles + shared B read (R24).
//
// Math (gate A rows pre-scaled by log2e for i,f,o / 2*log2e for g):
//   Ei=2^-i', Ef=2^-f', Eg=2^g', Eo=2^-o'
//   cs = [cs*(1+Ei)(1+Eg) + K2*(Eg-1)*(1+Ef)] * rcp((1+Ef)(1+Ei)(1+Eg))
//   Ec = 2^cs;  h = (Ec-1) * rcp((1+Eo)(1+Ec))
// K-slots: 0..49 = s*W_hh | 50 = (s*Wih)_hi (x_hi) | 51 = (s*bias)_hi (1.0)
//          52 = (s*Wih)_hi (x_lo) | 53 = (s*bias)_lo (1.0) | 54 = (s*Wih)_lo (x_hi)
//          55,56 = mixed-wave dump (h==0 there; A zero at k=55,56)
__global__ __launch_bounds__(NTH, 1) void lstm_mfma19_kernel(
    const float* __restrict__ x,      // [B, T]
    const float* __restrict__ W_ih,   // [200, 1]
    const float* __restrict__ W_hh,   // [200, 50]
    const float* __restrict__ b_ih,   // [200]
    const float* __restrict__ b_hh,   // [200]
    const float* __restrict__ W_out,  // [1, 50]
    const float* __restrict__ b_out,  // [1]
    float* __restrict__ out)          // [B, T]
{
    const int tid  = threadIdx.x;
    const int lane = tid & 63;
    const int wv   = tid >> 6;       // 0..6
    const int col  = lane & 15;      // A-m / B-n(batch) / D-col(batch)
    const int quad = lane >> 4;      // k-octet / D row-group

    __shared__ __align__(16) unsigned short Hh[2][BT][HS];

    // zero both H buffers (k-slots 55..63 + pads stay 0)
    for (int i = tid; i < 2 * BT * HS; i += NTH)
        (&Hh[0][0][0])[i] = 0;

    // persistent A fragments: [tile][kk] (single plane, PRE-SCALED rows)
    bf16x8 Ah[2][2];
    float cs0 = 0.f, cs1 = 0.f;                // per-tile cell state
    const int uoa = wv * 8 + quad;             // compute: tile-a unit (0..47)
    const int uob = wv * 8 + 4 + quad;         // compute: tile-b unit
    // mixed wave h slots: q1->48, q2->49, q0->55, q3->56
    const int uom = (quad == 1) ? 48 : (quad == 2) ? 49 : (quad == 0) ? 55 : 56;
    const int s0 = (wv < 6) ? uoa : uom;
    const int s1 = (wv < 6) ? uob : 57;        // 57: never written by mixed

    if (wv < 6) {
        #pragma unroll
        for (int i = 0; i < 2; ++i) {
            const int gh  = (wv * 2 + i) * 16 + col;   // g^ row (tiles 0..11)
            const int u   = gh >> 2;                   // unit 0..47 (all real)
            const int ty  = gh & 3;
            const int og  = ty * HID + u;              // original gate row
            const float sc = (ty == 2) ? K2C : L2E;
            #pragma unroll
            for (int kk = 0; kk < 2; ++kk) {
                #pragma unroll
                for (int j = 0; j < 8; ++j) {
                    const int k = kk * 32 + quad * 8 + j;
                    float v = 0.f;
                    if (k < HID)      v = sc * W_hh[og * HID + k];
                    else if (k == 50) v = sc * W_ih[og];
                    else if (k == 51) v = sc * (b_ih[og] + b_hh[og]);
                    else if (k == 52) v = sc * W_ih[og];
                    else if (k == 53) {
                        const float sb = sc * (b_ih[og] + b_hh[og]);
                        v = sb - bf16_f32(bf16_rtne(sb));
                    } else if (k == 54) {
                        const float sw = sc * W_ih[og];
                        v = sw - bf16_f32(bf16_rtne(sw));
                    }
                    Ah[i][kk][j] = (short)bf16_rtne(v);
                }
            }
        }
    } else {
        // mixed wave: rows 0,1 = y (hi/lo W_out, RAW, k<50 only);
        // rows 4..7 = unit 48 gates; rows 8..11 = unit 49; rest 0.
        #pragma unroll
        for (int kk = 0; kk < 2; ++kk) {
            #pragma unroll
            for (int j = 0; j < 8; ++j) {
                const int k = kk * 32 + quad * 8 + j;
                float v = 0.f;
                if (col < 2) {
                    if (k < HID) {
                        const float w = W_out[k];
                        v = (col == 0) ? w : w - bf16_f32(bf16_rtne(w));
                    }
                } else if (col >= 4 && col < 12) {
                    const int u  = (col < 8) ? 48 : 49;
                    const int ty = col & 3;
                    const int og = ty * HID + u;
                    const float sc = (ty == 2) ? K2C : L2E;
                    if (k < HID)      v = sc * W_hh[og * HID + k];
                    else if (k == 50) v = sc * W_ih[og];
                    else if (k == 51) v = sc * (b_ih[og] + b_hh[og]);
                    else if (k == 52) v = sc * W_ih[og];
                    else if (k == 53) {
                        const float sb = sc * (b_ih[og] + b_hh[og]);
                        v = sb - bf16_f32(bf16_rtne(sb));
                    } else if (k == 54) {
                        const float sw = sc * W_ih[og];
                        v = sw - bf16_f32(bf16_rtne(sw));
                    }
                }
                Ah[0][kk][j] = (short)bf16_rtne(v);
                Ah[1][kk][j] = 0;
            }
        }
    }
    const float bo = b_out[0];
    float* yout = out + (size_t)blockIdx.x * BT * TT + (size_t)col * TT;

    // x pipeline state (mixed wave, quad-3 lanes own batch b = col)
    const float* xrow = x + (size_t)(blockIdx.x * BT + col) * TT;
    float xa = 0.f;
    if (wv == 6 && lane >= 48)
        xa = xrow[1];                            // x[b][1] for step t=0's write

    __syncthreads();    // zeroed H visible

    // buffer-0 slots for t=0: x_0 hi/lo + bias-1.0 markers (packed b32 writes)
    if (tid < BT) {
        const float x0 = x[(size_t)(blockIdx.x * BT + tid) * TT];
        const unsigned short hx = bf16_rtne(x0);
        const unsigned short lx = bf16_rtne(x0 - bf16_f32(hx));
        unsigned* row32 = (unsigned*)&Hh[0][tid][0];
        row32[25] = (unsigned)hx | (0x3F80u << 16);   // k=50,51
        row32[26] = (unsigned)lx | (0x3F80u << 16);   // k=52,53
        Hh[0][tid][54] = hx;                          // k=54
    }
    __syncthreads();

    // hoisted per-lane pointers (loop-invariant)
    const unsigned short* rdA = &Hh[0][col][quad * 8];   // read plane 0
    const unsigned short* rdB = &Hh[1][col][quad * 8];   // read plane 1
    unsigned short* wrA0 = &Hh[1][col][s0];              // write when reading 0
    unsigned short* wrA1 = &Hh[1][col][s1];
    unsigned short* wrB0 = &Hh[0][col][s0];              // write when reading 1
    unsigned short* wrB1 = &Hh[0][col][s1];
    unsigned* xwA = (unsigned*)&Hh[1][col][0];
    unsigned* xwB = (unsigned*)&Hh[0][col][0];
    const f32x4 z = {0.f, 0.f, 0.f, 0.f};

#define GATES(ACC, CS, HOUT)                                                  \
    do {                                                                      \
        const float Ei = __builtin_amdgcn_exp2f(-(ACC).x);                    \
        const float Ef = __builtin_amdgcn_exp2f(-(ACC).y);                    \
        const float Eg = __builtin_amdgcn_exp2f((ACC).z);                     \
        const float Eo = __builtin_amdgcn_exp2f(-(ACC).w);                    \
        const float DIG = (1.f + Ei) * (1.f + Eg);                            \
        const float DF  = 1.f + Ef;                                           \
        const float t1  = fmaf(K2C, Eg, -K2C);                                \
        const float num = fmaf((CS), DIG, t1 * DF);                           \
        (CS) = num * __builtin_amdgcn_rcpf(DF * DIG);                         \
        const float Ec = __builtin_amdgcn_exp2f(CS);                          \
        (HOUT) = (Ec - 1.f) *                                                 \
                 __builtin_amdgcn_rcpf((1.f + Eo) * (1.f + Ec));              \
    } while (0)

#define LSTM_STEP(RD, WR0, WR1, XW, TI)                                       \
    do {                                                                      \
        const bf16x8 B0 = *(const bf16x8*)(RD);                               \
        const bf16x8 B1 = *(const bf16x8*)((RD) + 32);                        \
        if (wv < 6) {                                                         \
            f32x4 a0 = __builtin_amdgcn_mfma_f32_16x16x32_bf16(Ah[0][0], B0, z, 0, 0, 0); \
            f32x4 a1 = __builtin_amdgcn_mfma_f32_16x16x32_bf16(Ah[1][0], B0, z, 0, 0, 0); \
            a0 = __builtin_amdgcn_mfma_f32_16x16x32_bf16(Ah[0][1], B1, a0, 0, 0, 0); \
            a1 = __builtin_amdgcn_mfma_f32_16x16x32_bf16(Ah[1][1], B1, a1, 0, 0, 0); \
            float h0, h1;                                                     \
            GATES(a0, cs0, h0);                                               \
            GATES(a1, cs1, h1);                                               \
            unsigned hpk;                                                     \
            asm("v_cvt_pk_bf16_f32 %0, %1, %2" : "=v"(hpk) : "v"(h0), "v"(h1)); \
            *(WR0) = (unsigned short)(hpk & 0xFFFFu);                         \
            *(WR1) = (unsigned short)(hpk >> 16);                             \
        } else {                                                              \
            if (lane >= 48) {                                                 \
                const unsigned short hx = bf16_rtne(xa);                      \
                const unsigned short lx = bf16_rtne(xa - bf16_f32(hx));       \
                (XW)[25] = (unsigned)hx | (0x3F80u << 16);                    \
                (XW)[26] = (unsigned)lx | (0x3F80u << 16);                    \
                ((unsigned short*)(XW))[54] = hx;                             \
                xa = xrow[((TI) + 2 < TT) ? (TI) + 2 : TT - 1];               \
            }                                                                 \
            f32x4 a0 = __builtin_amdgcn_mfma_f32_16x16x32_bf16(Ah[0][0], B0, z, 0, 0, 0); \
            a0 = __builtin_amdgcn_mfma_f32_16x16x32_bf16(Ah[0][1], B1, a0, 0, 0, 0); \
            float h0;                                                         \
            GATES(a0, cs0, h0);                                               \
            unsigned hpk;                                                     \
            asm("v_cvt_pk_bf16_f32 %0, %1, %2" : "=v"(hpk) : "v"(h0), "v"(h0)); \
            *(WR0) = (unsigned short)(hpk & 0xFFFFu);                         \
            if (lane < 16 && (TI) > 0)                                        \
                yout[(TI) - 1] = a0.x + a0.y + bo;                            \
        }                                                                     \
    } while (0)

    for (int t = 0; t < TT; t += 2) {
        LSTM_STEP(rdA, wrA0, wrA1, xwA, t);        // read plane 0, write plane 1
        asm volatile("s_waitcnt lgkmcnt(0)\n\ts_barrier" ::: "memory");
        LSTM_STEP(rdB, wrB0, wrB1, xwB, t + 1);    // read plane 1, write plane 0
        asm volatile("s_waitcnt lgkmcnt(0)\n\ts_barrier" ::: "memory");
    }
#undef LSTM_STEP
#undef GATES

    // epilogue: y_{TT-1} from plane 0 (h_{511}) via the mixed wave's A
    if (wv == 6) {
        const bf16x8 B0 = *(const bf16x8*)rdA;
        const bf16x8 B1 = *(const bf16x8*)(rdA + 32);
        f32x4 a0 = __builtin_amdgcn_mfma_f32_16x16x32_bf16(Ah[0][0], B0, z, 0, 0, 0);
        a0 = __builtin_amdgcn_mfma_f32_16x16x32_bf16(Ah[0][1], B1, a0, 0, 0, 0);
        if (lane < 16)
            yout[TT - 1] = a0.x + a0.y + bo;
    }
}

extern "C" void kernel_launch(void* const* d_in, const int* in_sizes, int n_in,
                              void* d_out, int out_size, void* d_ws, size_t ws_size,
                              hipStream_t stream) {
    const float* x     = (const float*)d_in[0];
    const float* W_ih  = (const float*)d_in[1];
    const float* W_hh  = (const float*)d_in[2];
    const float* b_ih  = (const float*)d_in[3];
    const float* b_hh  = (const float*)d_in[4];
    const float* W_out = (const float*)d_in[5];
    const float* b_out = (const float*)d_in[6];
    float* out = (float*)d_out;

    const int B = in_sizes[0] / TT;          // 4096
    lstm_mfma19_kernel<<<B / BT, NTH, 0, stream>>>(x, W_ih, W_hh, b_ih, b_hh,
                                                   W_out, b_out, out);
}